// Round 4
// baseline (737.899 us; speedup 1.0000x reference)
//
#include <hip/hip_runtime.h>
#include <hip/hip_bf16.h>

#define N_CRYST 64
#define ATOMS_PER 32
#define NN 2048
#define NBRS 20
#define EE 40960
#define CC 128
#define HIDDIM 256
#define NBASIS 128
#define NLAYERS 8
#define LMAXV 6
#define KK 19
#define MAXZV 100
#define ZDIMV 256
#define FOUR_PI_F 12.566370614359172f

typedef unsigned short ushort_t;
typedef __attribute__((ext_vector_type(8))) short short8;
typedef __attribute__((ext_vector_type(4))) float floatx4;

__device__ __forceinline__ ushort_t f2us(float f) {
    union { float f; unsigned u; } x;
    x.f = f;
    unsigned r = (x.u + 0x7fffu + ((x.u >> 16) & 1u)) >> 16;
    return (ushort_t)r;
}
__device__ __forceinline__ float us2f(unsigned u) {  // low 16 bits = bf16
    return __uint_as_float(u << 16);
}

// ---------------- lattice + positions ----------------
__global__ void k_pos(const float* __restrict__ frac, const float* __restrict__ lengths,
                      const float* __restrict__ angles, const int* __restrict__ batch,
                      float* __restrict__ pos) {
    int n = blockIdx.x * blockDim.x + threadIdx.x;
    if (n >= NN) return;
    int b = batch[n];
    float la = lengths[b * 3 + 0];
    float lb = lengths[b * 3 + 1];
    float lc = lengths[b * 3 + 2];
    const float D2R = 0.017453292519943295f;
    float aa = angles[b * 3 + 0] * D2R;
    float ab = angles[b * 3 + 1] * D2R;
    float ag = angles[b * 3 + 2] * D2R;
    float ca = cosf(aa), cb = cosf(ab), cg = cosf(ag), sg = sinf(ag);
    float v3y = (ca - cb * cg) / sg;
    float v3z = sqrtf(fmaxf(1.0f - cb * cb - v3y * v3y, 1e-8f));
    float f0 = frac[n * 3 + 0];
    float f1 = frac[n * 3 + 1];
    float f2 = frac[n * 3 + 2];
    pos[n * 3 + 0] = f0 * la + f1 * (lb * cg) + f2 * (lc * cb);
    pos[n * 3 + 1] = f1 * (lb * sg) + f2 * (lc * v3y);
    pos[n * 3 + 2] = f2 * (lc * v3z);
}

// ---------------- edge geometry ----------------
__global__ void k_edge(const int* __restrict__ ei, const float* __restrict__ pos,
                       float* __restrict__ dist, float* __restrict__ dirn,
                       float* __restrict__ Yv) {
    int e = blockIdx.x * blockDim.x + threadIdx.x;
    if (e >= EE) return;
    int s = ei[e], d = ei[EE + e];
    float vx = pos[s * 3 + 0] - pos[d * 3 + 0];
    float vy = pos[s * 3 + 1] - pos[d * 3 + 1];
    float vz = pos[s * 3 + 2] - pos[d * 3 + 2];
    float dd = sqrtf(vx * vx + vy * vy + vz * vz) + 1e-8f;
    float ix = vx / dd, iy = vy / dd, iz = vz / dd;
    dist[e] = dd;
    dirn[e * 3 + 0] = ix;
    dirn[e * 3 + 1] = iy;
    dirn[e * 3 + 2] = iz;

    float ct = iz;
    float rho = sqrtf(ix * ix + iy * iy) + 1e-12f;
    float cph = ix / rho, sph = iy / rho;
    float P0[LMAXV + 1];
    float P1[LMAXV + 1];
    P0[0] = 1.0f;
    P0[1] = ct;
    #pragma unroll
    for (int l = 2; l <= LMAXV; l++)
        P0[l] = ((2 * l - 1) * ct * P0[l - 1] - (l - 1) * P0[l - 2]) / (float)l;
    P1[0] = 0.0f;
    P1[1] = -rho;
    P1[2] = -3.0f * ct * rho;
    #pragma unroll
    for (int l = 3; l <= LMAXV; l++)
        P1[l] = ((2 * l - 1) * ct * P1[l - 1] - l * P1[l - 2]) / (float)(l - 1);

    float* Ye = Yv + (size_t)e * KK;
    Ye[0] = 0.28209479177387814f;
    #pragma unroll
    for (int l = 1; l <= LMAXV; l++) {
        float K0 = sqrtf((2 * l + 1) / FOUR_PI_F);
        float K1 = sqrtf(2.0f * (2 * l + 1) / (FOUR_PI_F * l * (l + 1)));
        Ye[3 * l - 2] = K1 * P1[l] * sph;
        Ye[3 * l - 1] = K0 * P0[l];
        Ye[3 * l]     = K1 * P1[l] * cph;
    }
}

// ---------------- CSR by source atom (layer-invariant) + permuted padded Y ----------------
__global__ void k_csr(const int* __restrict__ ei, const float* __restrict__ Yv,
                      int* __restrict__ rowptr, int* __restrict__ origid,
                      float* __restrict__ Yp) {
    int cr = blockIdx.x;  // 64 blocks x 64 threads
    int t = threadIdx.x;
    __shared__ int cnt[32], base[32];
    if (t < 32) cnt[t] = 0;
    __syncthreads();
    for (int j = t; j < 640; j += 64) {
        int a = ei[cr * 640 + j] - cr * 32;
        atomicAdd(&cnt[a], 1);
    }
    __syncthreads();
    if (t == 0) {
        int run = 0;
        for (int a = 0; a < 32; a++) {
            base[a] = run;
            rowptr[cr * 33 + a] = run;
            run += cnt[a];
        }
        rowptr[cr * 33 + 32] = run;
    }
    __syncthreads();
    if (t < 32) cnt[t] = 0;
    __syncthreads();
    for (int j = t; j < 640; j += 64) {
        int e = cr * 640 + j;
        int a = ei[e] - cr * 32;
        int slot = base[a] + atomicAdd(&cnt[a], 1);
        int p = cr * 640 + slot;
        origid[p] = e;
        float* yp = Yp + (size_t)p * 20;
        #pragma unroll
        for (int k = 0; k < KK; k++) yp[k] = Yv[(size_t)e * KK + k];
        yp[19] = 0.0f;
    }
}

// ---------------- rbf -> bf16 into A-buffer cols [128,256) (layer-invariant) ----------------
__global__ void k_rbfA(const float* __restrict__ dist, ushort_t* __restrict__ Abf) {
    int idx = blockIdx.x * blockDim.x + threadIdx.x;
    if (idx >= EE * NBASIS) return;
    int e = idx >> 7, j = idx & 127;
    const float width = 8.0f / 127.0f;
    const float invw = 127.0f / 8.0f;
    float t = (dist[e] - (float)j * width) * invw;
    Abf[(size_t)e * 256 + 128 + j] = f2us(expf(-0.5f * t * t));
}

// ---------------- weight transpose+cast ----------------
__global__ void k_wt(const float* __restrict__ W1, const float* __restrict__ Wd,
                     const float* __restrict__ W2,
                     ushort_t* __restrict__ WT1, ushort_t* __restrict__ WT2) {
    int idx = blockIdx.x * blockDim.x + threadIdx.x;
    const int n1 = NLAYERS * HIDDIM * 256;
    if (idx < n1) {
        int l = idx >> 16;
        int r = idx & 65535;
        int n = r >> 8, k = r & 255;
        float v = (k < 128) ? W1[((size_t)l * CC + k) * HIDDIM + n]
                            : Wd[((size_t)l * NBASIS + (k - 128)) * HIDDIM + n];
        WT1[idx] = f2us(v);
    } else {
        int j = idx - n1;
        if (j >= NLAYERS * CC * HIDDIM) return;
        int l = j >> 15;
        int r = j & 32767;
        int n = r >> 8, k = r & 255;
        WT2[j] = f2us(W2[((size_t)l * HIDDIM + k) * CC + n]);
    }
}

// ---------------- z @ zproj ----------------
__global__ void k_zc(const float* __restrict__ z, const float* __restrict__ zproj,
                     float* __restrict__ zc) {
    int idx = blockIdx.x * blockDim.x + threadIdx.x;
    if (idx >= N_CRYST * CC) return;
    int b = idx >> 7, c = idx & 127;
    float acc = 0.0f;
    for (int d = 0; d < ZDIMV; d++)
        acc += z[b * ZDIMV + d] * zproj[d * CC + c];
    zc[idx] = acc;
}

// ---------------- init x ----------------
__global__ void k_xinit(const int* __restrict__ atype, const int* __restrict__ batch,
                        const float* __restrict__ emb, const float* __restrict__ zc,
                        float* __restrict__ x) {
    int idx = blockIdx.x * blockDim.x + threadIdx.x;
    if (idx >= NN * KK * CC) return;
    int n = idx / (KK * CC);
    int r = idx - n * (KK * CC);
    float v = 0.0f;
    if (r < CC) v = emb[atype[n] * CC + r] + zc[batch[n] * CC + r];
    x[idx] = v;
}

// ---------------- s via CSR: thread = (atom, col-quad), x slice in registers ----------------
// grid 256 = (crystal, 32-col block); 256 threads = 32 atoms x 8 col-quads.
__global__ __launch_bounds__(256) void k_s2(const int* __restrict__ rowptr,
                                            const int* __restrict__ origid,
                                            const float* __restrict__ Yp,
                                            const float* __restrict__ x,
                                            ushort_t* __restrict__ Abf) {
    int cr = blockIdx.x >> 2;
    int cbase = (blockIdx.x & 3) * 32;
    int t = threadIdx.x;
    int a = t >> 3;
    int cq = cbase + (t & 7) * 4;

    float4 xr[20];
    const float* xp = x + (size_t)(cr * 32 + a) * (KK * CC) + cq;
    #pragma unroll
    for (int k = 0; k < KK; k++) xr[k] = *(const float4*)(xp + k * CC);
    xr[19] = make_float4(0.f, 0.f, 0.f, 0.f);

    int i0 = rowptr[cr * 33 + a], i1 = rowptr[cr * 33 + a + 1];
    for (int i = i0; i < i1; i++) {
        int p = cr * 640 + i;
        const float* yp = Yp + (size_t)p * 20;
        float ax = 0.f, ay = 0.f, az = 0.f, aw = 0.f;
        #pragma unroll
        for (int kq = 0; kq < 5; kq++) {
            float4 y = *(const float4*)(yp + kq * 4);
            float4 x0 = xr[kq * 4 + 0], x1 = xr[kq * 4 + 1];
            float4 x2 = xr[kq * 4 + 2], x3 = xr[kq * 4 + 3];
            ax += y.x * x0.x + y.y * x1.x + y.z * x2.x + y.w * x3.x;
            ay += y.x * x0.y + y.y * x1.y + y.z * x2.y + y.w * x3.y;
            az += y.x * x0.z + y.y * x1.z + y.z * x2.z + y.w * x3.z;
            aw += y.x * x0.w + y.y * x1.w + y.z * x2.w + y.w * x3.w;
        }
        int e = origid[p];
        unsigned lo = ((unsigned)f2us(ax)) | (((unsigned)f2us(ay)) << 16);
        unsigned hi = ((unsigned)f2us(az)) | (((unsigned)f2us(aw)) << 16);
        uint2 pk; pk.x = lo; pk.y = hi;
        *(uint2*)&Abf[(size_t)e * 256 + cq] = pk;
    }
}

// ---------------- GEMM1: h = silu(A[E,256] @ WT1^T) -> bf16 ----------------
#define LDK 72
__global__ __launch_bounds__(256) void k_gemm1(const ushort_t* __restrict__ A,
                                               const ushort_t* __restrict__ BT,
                                               ushort_t* __restrict__ hout) {
    __shared__ ushort_t Alds[128 * LDK];
    __shared__ ushort_t Blds[128 * LDK];
    int t = threadIdx.x;
    int e0 = blockIdx.x * 128;
    int n0 = blockIdx.y * 128;
    int w = t >> 6, lane = t & 63;
    int wm = (w & 1) * 64, wn = (w >> 1) * 64;
    int quad = lane >> 4, lrow = lane & 15;

    floatx4 acc[4][4];
    #pragma unroll
    for (int mi = 0; mi < 4; mi++)
        #pragma unroll
        for (int ni = 0; ni < 4; ni++)
            acc[mi][ni] = (floatx4){0.0f, 0.0f, 0.0f, 0.0f};

    for (int k0 = 0; k0 < 256; k0 += 64) {
        #pragma unroll
        for (int i = 0; i < 4; i++) {
            int idx = i * 256 + t;
            int r = idx >> 3, kc = (idx & 7) * 8;
            *(short8*)&Alds[r * LDK + kc] =
                *(const short8*)&A[(size_t)(e0 + r) * 256 + k0 + kc];
            *(short8*)&Blds[r * LDK + kc] =
                *(const short8*)&BT[(size_t)(n0 + r) * 256 + k0 + kc];
        }
        __syncthreads();
        #pragma unroll
        for (int kk = 0; kk < 64; kk += 32) {
            short8 af[4], bfr[4];
            #pragma unroll
            for (int i = 0; i < 4; i++) {
                af[i]  = *(const short8*)&Alds[(wm + i * 16 + lrow) * LDK + kk + quad * 8];
                bfr[i] = *(const short8*)&Blds[(wn + i * 16 + lrow) * LDK + kk + quad * 8];
            }
            #pragma unroll
            for (int mi = 0; mi < 4; mi++)
                #pragma unroll
                for (int ni = 0; ni < 4; ni++)
                    acc[mi][ni] = __builtin_amdgcn_mfma_f32_16x16x32_bf16(
                        af[mi], bfr[ni], acc[mi][ni], 0, 0, 0);
        }
        __syncthreads();
    }

    #pragma unroll
    for (int mi = 0; mi < 4; mi++) {
        int row = e0 + wm + mi * 16 + quad * 4;
        #pragma unroll
        for (int ni = 0; ni < 4; ni++) {
            int col = n0 + wn + ni * 16 + lrow;
            #pragma unroll
            for (int r = 0; r < 4; r++) {
                float v = acc[mi][ni][r];
                v = v / (1.0f + __expf(-v));
                hout[(size_t)(row + r) * 256 + col] = f2us(v);
            }
        }
    }
}

// ---------------- GEMM2 + fused aggregation ----------------
// M-tile 160 edges = 8 nodes exactly; grid 256 blocks; 4 waves 2x2 (wave tile 80x64).
__global__ __launch_bounds__(256) void k_gemm2agg(const ushort_t* __restrict__ hbuf,
                                                  const ushort_t* __restrict__ BT,
                                                  const float* __restrict__ Yv,
                                                  float* __restrict__ x) {
    __shared__ union {
        struct { ushort_t A[160 * LDK]; ushort_t B[128 * LDK]; } g;
        ushort_t m[160 * 128];
    } sm;
    __shared__ float Ylds[160 * 20];
    int t = threadIdx.x;
    int e0 = blockIdx.x * 160;

    for (int i = t; i < 160 * 20; i += 256) {
        int e = i / 20, k = i - (i / 20) * 20;
        Ylds[i] = (k < KK) ? Yv[(size_t)(e0 + e) * KK + k] : 0.0f;
    }

    int w = t >> 6, lane = t & 63;
    int wm = (w & 1) * 80, wn = (w >> 1) * 64;
    int quad = lane >> 4, lrow = lane & 15;

    floatx4 acc[5][4];
    #pragma unroll
    for (int mi = 0; mi < 5; mi++)
        #pragma unroll
        for (int ni = 0; ni < 4; ni++)
            acc[mi][ni] = (floatx4){0.0f, 0.0f, 0.0f, 0.0f};

    for (int k0 = 0; k0 < 256; k0 += 64) {
        #pragma unroll
        for (int i = 0; i < 5; i++) {  // A: 160 rows x 64 cols
            int idx = i * 256 + t;
            int r = idx >> 3, kc = (idx & 7) * 8;
            *(short8*)&sm.g.A[r * LDK + kc] =
                *(const short8*)&hbuf[(size_t)(e0 + r) * 256 + k0 + kc];
        }
        #pragma unroll
        for (int i = 0; i < 4; i++) {  // B: 128 rows x 64 cols
            int idx = i * 256 + t;
            int r = idx >> 3, kc = (idx & 7) * 8;
            *(short8*)&sm.g.B[r * LDK + kc] =
                *(const short8*)&BT[(size_t)r * 256 + k0 + kc];
        }
        __syncthreads();
        #pragma unroll
        for (int kk = 0; kk < 64; kk += 32) {
            short8 af[5], bfr[4];
            #pragma unroll
            for (int mi = 0; mi < 5; mi++)
                af[mi] = *(const short8*)&sm.g.A[(wm + mi * 16 + lrow) * LDK + kk + quad * 8];
            #pragma unroll
            for (int ni = 0; ni < 4; ni++)
                bfr[ni] = *(const short8*)&sm.g.B[(wn + ni * 16 + lrow) * LDK + kk + quad * 8];
            #pragma unroll
            for (int mi = 0; mi < 5; mi++)
                #pragma unroll
                for (int ni = 0; ni < 4; ni++)
                    acc[mi][ni] = __builtin_amdgcn_mfma_f32_16x16x32_bf16(
                        af[mi], bfr[ni], acc[mi][ni], 0, 0, 0);
        }
        __syncthreads();
    }

    // write m tile to LDS as bf16 (aliases A/B staging — safe after barrier)
    #pragma unroll
    for (int mi = 0; mi < 5; mi++) {
        int row = wm + mi * 16 + quad * 4;
        #pragma unroll
        for (int ni = 0; ni < 4; ni++) {
            int col = wn + ni * 16 + lrow;
            #pragma unroll
            for (int r = 0; r < 4; r++)
                sm.m[(row + r) * 128 + col] = f2us(acc[mi][ni][r]);
        }
    }
    __syncthreads();

    // aggregation: thread = (node 0..7, col-quad 0..31)
    int node = t >> 5;
    int cq = (t & 31) * 4;
    float4 xacc[KK];
    #pragma unroll
    for (int k = 0; k < KK; k++) xacc[k] = make_float4(0.f, 0.f, 0.f, 0.f);

    for (int e = 0; e < NBRS; e++) {
        int eg = node * NBRS + e;
        uint2 mv = *(const uint2*)&sm.m[eg * 128 + cq];
        float4 mf;
        mf.x = us2f(mv.x & 0xffffu);
        mf.y = us2f(mv.x >> 16);
        mf.z = us2f(mv.y & 0xffffu);
        mf.w = us2f(mv.y >> 16);
        const float* yp = &Ylds[eg * 20];
        #pragma unroll
        for (int kq = 0; kq < 5; kq++) {
            float4 y = *(const float4*)(yp + kq * 4);
            int k = kq * 4;
            xacc[k + 0].x += y.x * mf.x; xacc[k + 0].y += y.x * mf.y;
            xacc[k + 0].z += y.x * mf.z; xacc[k + 0].w += y.x * mf.w;
            xacc[k + 1].x += y.y * mf.x; xacc[k + 1].y += y.y * mf.y;
            xacc[k + 1].z += y.y * mf.z; xacc[k + 1].w += y.y * mf.w;
            xacc[k + 2].x += y.z * mf.x; xacc[k + 2].y += y.z * mf.y;
            xacc[k + 2].z += y.z * mf.z; xacc[k + 2].w += y.z * mf.w;
            if (kq < 4) {
                xacc[k + 3].x += y.w * mf.x; xacc[k + 3].y += y.w * mf.y;
                xacc[k + 3].z += y.w * mf.z; xacc[k + 3].w += y.w * mf.w;
            }
        }
    }
    const float s = 1.0f / (float)NBRS;
    int ng = blockIdx.x * 8 + node;
    float* xp = x + (size_t)ng * (KK * CC) + cq;
    #pragma unroll
    for (int k = 0; k < KK; k++) {
        float4 old = *(const float4*)(xp + k * CC);
        old.x += xacc[k].x * s; old.y += xacc[k].y * s;
        old.z += xacc[k].z * s; old.w += xacc[k].w * s;
        *(float4*)(xp + k * CC) = old;
    }
}

// ---------------- atom logits ----------------
__global__ void k_logits(const float* __restrict__ x, const float* __restrict__ Wa,
                         const float* __restrict__ ba, float* __restrict__ out) {
    int idx = blockIdx.x * blockDim.x + threadIdx.x;
    if (idx >= NN * MAXZV) return;
    int n = idx / MAXZV, a = idx - n * MAXZV;
    float acc = ba[a];
    const float* hn = x + (size_t)n * (KK * CC);
    for (int c = 0; c < CC; c++) acc += hn[c] * Wa[c * MAXZV + a];
    out[idx] = acc;
}

// ---------------- coord_diff ----------------
__global__ void k_coord(const int* __restrict__ ei, const float* __restrict__ x,
                        const float* __restrict__ wf, const float* __restrict__ dirn,
                        float* __restrict__ out) {
    int n = blockIdx.x;
    int t = threadIdx.x;  // 64
    __shared__ float fs[NBRS];
    __shared__ float wsh[CC];
    wsh[t] = wf[t];
    wsh[t + 64] = wf[t + 64];
    __syncthreads();
    if (t < NBRS) {
        int e = n * NBRS + t;
        int sidx = ei[e];
        const float* xs = x + (size_t)sidx * (KK * CC);
        const float* xd = x + (size_t)n * (KK * CC);
        float acc = 0.0f;
        for (int c = 0; c < CC; c++) acc += (xs[c] - xd[c]) * wsh[c];
        fs[t] = acc;
    }
    __syncthreads();
    if (t < 3) {
        float acc = 0.0f;
        #pragma unroll
        for (int j = 0; j < NBRS; j++) acc += fs[j] * dirn[(size_t)(n * NBRS + j) * 3 + t];
        out[n * 3 + t] = acc;
    }
}

extern "C" void kernel_launch(void* const* d_in, const int* in_sizes, int n_in,
                              void* d_out, int out_size, void* d_ws, size_t ws_size,
                              hipStream_t stream) {
    (void)in_sizes; (void)n_in; (void)out_size; (void)ws_size;
    const float* z       = (const float*)d_in[0];
    const float* frac    = (const float*)d_in[1];
    const int*   atype   = (const int*)d_in[2];
    const float* lengths = (const float*)d_in[4];
    const float* angles  = (const float*)d_in[5];
    const int*   batch   = (const int*)d_in[6];
    const int*   ei      = (const int*)d_in[7];
    const float* emb     = (const float*)d_in[8];
    const float* zproj   = (const float*)d_in[9];
    const float* Wd      = (const float*)d_in[10];
    const float* W1      = (const float*)d_in[11];
    const float* W2      = (const float*)d_in[12];
    const float* Wa      = (const float*)d_in[13];
    const float* ba      = (const float*)d_in[14];
    const float* wf      = (const float*)d_in[15];
    float* out = (float*)d_out;

    float* ws = (float*)d_ws;
    float* pos  = ws; ws += NN * 3 + 4;         // keep 16B alignment
    float* dist = ws; ws += EE;
    float* dirn = ws; ws += EE * 3;
    float* Yv   = ws; ws += (size_t)EE * KK + 4;
    float* Yp   = ws; ws += (size_t)EE * 20;    // permuted, padded to 20
    float* zc   = ws; ws += N_CRYST * CC;
    float* x    = ws; ws += (size_t)NN * KK * CC;
    int* rowptr = (int*)ws;                      // 64*33
    int* origid = rowptr + 64 * 33 + 3;          // EE (keep 16B align)
    ushort_t* Abf  = (ushort_t*)(origid + EE);   // [E][256]
    ushort_t* hbuf = Abf + (size_t)EE * 256;     // [E][256]
    ushort_t* WT1  = hbuf + (size_t)EE * 256;    // [8][256][256]
    ushort_t* WT2  = WT1 + (size_t)NLAYERS * 256 * 256;  // [8][128][256]

    k_pos<<<NN / 256, 256, 0, stream>>>(frac, lengths, angles, batch, pos);
    k_edge<<<EE / 256, 256, 0, stream>>>(ei, pos, dist, dirn, Yv);
    k_csr<<<N_CRYST, 64, 0, stream>>>(ei, Yv, rowptr, origid, Yp);
    k_rbfA<<<(EE * NBASIS) / 256, 256, 0, stream>>>(dist, Abf);
    k_wt<<<(NLAYERS * (HIDDIM * 256 + CC * HIDDIM)) / 256, 256, 0, stream>>>(W1, Wd, W2, WT1, WT2);
    k_zc<<<(N_CRYST * CC) / 256, 256, 0, stream>>>(z, zproj, zc);
    k_xinit<<<(NN * KK * CC) / 256, 256, 0, stream>>>(atype, batch, emb, zc, x);

    for (int l = 0; l < NLAYERS; l++) {
        k_s2<<<256, 256, 0, stream>>>(rowptr, origid, Yp, x, Abf);
        k_gemm1<<<dim3(EE / 128, 2), 256, 0, stream>>>(
            Abf, WT1 + (size_t)l * 256 * 256, hbuf);
        k_gemm2agg<<<256, 256, 0, stream>>>(
            hbuf, WT2 + (size_t)l * CC * HIDDIM, Yv, x);
    }

    k_coord<<<NN, 64, 0, stream>>>(ei, x, wf, dirn, out);
    k_logits<<<(NN * MAXZV) / 256, 256, 0, stream>>>(x, Wa, ba, out + NN * 3);
}

// Round 5
// 600.830 us; speedup vs baseline: 1.2281x; 1.2281x over previous
//
#include <hip/hip_runtime.h>
#include <hip/hip_bf16.h>

#define N_CRYST 64
#define ATOMS_PER 32
#define NN 2048
#define NBRS 20
#define EE 40960
#define CC 128
#define HIDDIM 256
#define NBASIS 128
#define NLAYERS 8
#define LMAXV 6
#define KK 19
#define MAXZV 100
#define ZDIMV 256
#define FOUR_PI_F 12.566370614359172f

typedef unsigned short ushort_t;
typedef __attribute__((ext_vector_type(8))) short short8;
typedef __attribute__((ext_vector_type(4))) float floatx4;

__device__ __forceinline__ ushort_t f2us(float f) {
    union { float f; unsigned u; } x;
    x.f = f;
    unsigned r = (x.u + 0x7fffu + ((x.u >> 16) & 1u)) >> 16;
    return (ushort_t)r;
}
__device__ __forceinline__ float us2f(unsigned u) {  // low 16 bits = bf16
    return __uint_as_float(u << 16);
}

// ---------------- lattice + positions ----------------
__global__ void k_pos(const float* __restrict__ frac, const float* __restrict__ lengths,
                      const float* __restrict__ angles, const int* __restrict__ batch,
                      float* __restrict__ pos) {
    int n = blockIdx.x * blockDim.x + threadIdx.x;
    if (n >= NN) return;
    int b = batch[n];
    float la = lengths[b * 3 + 0];
    float lb = lengths[b * 3 + 1];
    float lc = lengths[b * 3 + 2];
    const float D2R = 0.017453292519943295f;
    float aa = angles[b * 3 + 0] * D2R;
    float ab = angles[b * 3 + 1] * D2R;
    float ag = angles[b * 3 + 2] * D2R;
    float ca = cosf(aa), cb = cosf(ab), cg = cosf(ag), sg = sinf(ag);
    float v3y = (ca - cb * cg) / sg;
    float v3z = sqrtf(fmaxf(1.0f - cb * cb - v3y * v3y, 1e-8f));
    float f0 = frac[n * 3 + 0];
    float f1 = frac[n * 3 + 1];
    float f2 = frac[n * 3 + 2];
    pos[n * 3 + 0] = f0 * la + f1 * (lb * cg) + f2 * (lc * cb);
    pos[n * 3 + 1] = f1 * (lb * sg) + f2 * (lc * v3y);
    pos[n * 3 + 2] = f2 * (lc * v3z);
}

// ---------------- edge geometry ----------------
__global__ void k_edge(const int* __restrict__ ei, const float* __restrict__ pos,
                       float* __restrict__ dist, float* __restrict__ dirn,
                       float* __restrict__ Yv) {
    int e = blockIdx.x * blockDim.x + threadIdx.x;
    if (e >= EE) return;
    int s = ei[e], d = ei[EE + e];
    float vx = pos[s * 3 + 0] - pos[d * 3 + 0];
    float vy = pos[s * 3 + 1] - pos[d * 3 + 1];
    float vz = pos[s * 3 + 2] - pos[d * 3 + 2];
    float dd = sqrtf(vx * vx + vy * vy + vz * vz) + 1e-8f;
    float ix = vx / dd, iy = vy / dd, iz = vz / dd;
    dist[e] = dd;
    dirn[e * 3 + 0] = ix;
    dirn[e * 3 + 1] = iy;
    dirn[e * 3 + 2] = iz;

    float ct = iz;
    float rho = sqrtf(ix * ix + iy * iy) + 1e-12f;
    float cph = ix / rho, sph = iy / rho;
    float P0[LMAXV + 1];
    float P1[LMAXV + 1];
    P0[0] = 1.0f;
    P0[1] = ct;
    #pragma unroll
    for (int l = 2; l <= LMAXV; l++)
        P0[l] = ((2 * l - 1) * ct * P0[l - 1] - (l - 1) * P0[l - 2]) / (float)l;
    P1[0] = 0.0f;
    P1[1] = -rho;
    P1[2] = -3.0f * ct * rho;
    #pragma unroll
    for (int l = 3; l <= LMAXV; l++)
        P1[l] = ((2 * l - 1) * ct * P1[l - 1] - l * P1[l - 2]) / (float)(l - 1);

    float* Ye = Yv + (size_t)e * KK;
    Ye[0] = 0.28209479177387814f;
    #pragma unroll
    for (int l = 1; l <= LMAXV; l++) {
        float K0 = sqrtf((2 * l + 1) / FOUR_PI_F);
        float K1 = sqrtf(2.0f * (2 * l + 1) / (FOUR_PI_F * l * (l + 1)));
        Ye[3 * l - 2] = K1 * P1[l] * sph;
        Ye[3 * l - 1] = K0 * P0[l];
        Ye[3 * l]     = K1 * P1[l] * cph;
    }
}

// ---------------- CSR by source atom (layer-invariant) + permuted padded Y ----------------
__global__ void k_csr(const int* __restrict__ ei, const float* __restrict__ Yv,
                      int* __restrict__ rowptr, int* __restrict__ origid,
                      float* __restrict__ Yp) {
    int cr = blockIdx.x;  // 64 blocks x 64 threads
    int t = threadIdx.x;
    __shared__ int cnt[32], base[32];
    if (t < 32) cnt[t] = 0;
    __syncthreads();
    for (int j = t; j < 640; j += 64) {
        int a = ei[cr * 640 + j] - cr * 32;
        atomicAdd(&cnt[a], 1);
    }
    __syncthreads();
    if (t == 0) {
        int run = 0;
        for (int a = 0; a < 32; a++) {
            base[a] = run;
            rowptr[cr * 33 + a] = run;
            run += cnt[a];
        }
        rowptr[cr * 33 + 32] = run;
    }
    __syncthreads();
    if (t < 32) cnt[t] = 0;
    __syncthreads();
    for (int j = t; j < 640; j += 64) {
        int e = cr * 640 + j;
        int a = ei[e] - cr * 32;
        int slot = base[a] + atomicAdd(&cnt[a], 1);
        int p = cr * 640 + slot;
        origid[p] = e;
        float* yp = Yp + (size_t)p * 20;
        #pragma unroll
        for (int k = 0; k < KK; k++) yp[k] = Yv[(size_t)e * KK + k];
        yp[19] = 0.0f;
    }
}

// ---------------- rbf -> bf16 into A-buffer cols [128,256) (layer-invariant) ----------------
__global__ void k_rbfA(const float* __restrict__ dist, ushort_t* __restrict__ Abf) {
    int idx = blockIdx.x * blockDim.x + threadIdx.x;
    if (idx >= EE * NBASIS) return;
    int e = idx >> 7, j = idx & 127;
    const float width = 8.0f / 127.0f;
    const float invw = 127.0f / 8.0f;
    float t = (dist[e] - (float)j * width) * invw;
    Abf[(size_t)e * 256 + 128 + j] = f2us(expf(-0.5f * t * t));
}

// ---------------- weight transpose+cast ----------------
__global__ void k_wt(const float* __restrict__ W1, const float* __restrict__ Wd,
                     const float* __restrict__ W2,
                     ushort_t* __restrict__ WT1, ushort_t* __restrict__ WT2) {
    int idx = blockIdx.x * blockDim.x + threadIdx.x;
    const int n1 = NLAYERS * HIDDIM * 256;
    if (idx < n1) {
        int l = idx >> 16;
        int r = idx & 65535;
        int n = r >> 8, k = r & 255;
        float v = (k < 128) ? W1[((size_t)l * CC + k) * HIDDIM + n]
                            : Wd[((size_t)l * NBASIS + (k - 128)) * HIDDIM + n];
        WT1[idx] = f2us(v);
    } else {
        int j = idx - n1;
        if (j >= NLAYERS * CC * HIDDIM) return;
        int l = j >> 15;
        int r = j & 32767;
        int n = r >> 8, k = r & 255;
        WT2[j] = f2us(W2[((size_t)l * HIDDIM + k) * CC + n]);
    }
}

// ---------------- z @ zproj ----------------
__global__ void k_zc(const float* __restrict__ z, const float* __restrict__ zproj,
                     float* __restrict__ zc) {
    int idx = blockIdx.x * blockDim.x + threadIdx.x;
    if (idx >= N_CRYST * CC) return;
    int b = idx >> 7, c = idx & 127;
    float acc = 0.0f;
    for (int d = 0; d < ZDIMV; d++)
        acc += z[b * ZDIMV + d] * zproj[d * CC + c];
    zc[idx] = acc;
}

// ---------------- init x ----------------
__global__ void k_xinit(const int* __restrict__ atype, const int* __restrict__ batch,
                        const float* __restrict__ emb, const float* __restrict__ zc,
                        float* __restrict__ x) {
    int idx = blockIdx.x * blockDim.x + threadIdx.x;
    if (idx >= NN * KK * CC) return;
    int n = idx / (KK * CC);
    int r = idx - n * (KK * CC);
    float v = 0.0f;
    if (r < CC) v = emb[atype[n] * CC + r] + zc[batch[n] * CC + r];
    x[idx] = v;
}

// ---------------- s via CSR: thread = (atom, col-pair), x slice in registers ----------------
// grid 512 = (crystal, 16-col block); 256 threads = 32 atoms x 8 col-pairs.
__global__ __launch_bounds__(256) void k_s2(const int* __restrict__ rowptr,
                                            const int* __restrict__ origid,
                                            const float* __restrict__ Yp,
                                            const float* __restrict__ x,
                                            ushort_t* __restrict__ Abf) {
    int cr = blockIdx.x >> 3;
    int cbase = (blockIdx.x & 7) * 16;
    int t = threadIdx.x;
    int a = t >> 3;
    int c2 = cbase + (t & 7) * 2;

    float2 xr[20];
    const float* xp = x + (size_t)(cr * 32 + a) * (KK * CC) + c2;
    #pragma unroll
    for (int k = 0; k < KK; k++) xr[k] = *(const float2*)(xp + k * CC);
    xr[19] = make_float2(0.f, 0.f);

    int i0 = rowptr[cr * 33 + a], i1 = rowptr[cr * 33 + a + 1];
    for (int i = i0; i < i1; i++) {
        int p = cr * 640 + i;
        const float* yp = Yp + (size_t)p * 20;
        float ax = 0.f, ay = 0.f;
        #pragma unroll
        for (int kq = 0; kq < 5; kq++) {
            float4 y = *(const float4*)(yp + kq * 4);
            float2 x0 = xr[kq * 4 + 0], x1 = xr[kq * 4 + 1];
            float2 x2 = xr[kq * 4 + 2], x3 = xr[kq * 4 + 3];
            ax += y.x * x0.x + y.y * x1.x + y.z * x2.x + y.w * x3.x;
            ay += y.x * x0.y + y.y * x1.y + y.z * x2.y + y.w * x3.y;
        }
        int e = origid[p];
        unsigned pk = (unsigned)f2us(ax) | (((unsigned)f2us(ay)) << 16);
        *(unsigned*)&Abf[(size_t)e * 256 + c2] = pk;
    }
}

// ---------------- fused GEMM1 + GEMM2 + aggregation per 8-node tile ----------------
// grid 256, block 256 (4 waves 2x2). h kept in registers across 4 n-chunks.
// LDS 59904 B: [0,23040) A-chunk[160][72] (later H / part of M)
//              [23040,59904) B[256][72] gemm1 / B2[128][72] gemm2
//              M[160][132] spans [0,42240); Ylds floats at [42240,55040)
__global__ __launch_bounds__(256, 1) void k_fused(const ushort_t* __restrict__ Abf,
                                                  const ushort_t* __restrict__ WT1,
                                                  const ushort_t* __restrict__ WT2,
                                                  const float* __restrict__ Yv,
                                                  float* __restrict__ x) {
    __shared__ char smraw[59904];
    ushort_t* As = (ushort_t*)smraw;
    ushort_t* Bs = (ushort_t*)(smraw + 23040);
    ushort_t* Hs = (ushort_t*)smraw;
    ushort_t* Ms = (ushort_t*)smraw;
    float* Ylds = (float*)(smraw + 42240);

    int t = threadIdx.x;
    int e0 = blockIdx.x * 160;
    int w = t >> 6, lane = t & 63;
    int quad = lane >> 4, lrow = lane & 15;
    int wm = (w & 1) * 80;
    int wn1 = (w >> 1) * 32;
    int wn2 = (w >> 1) * 64;

    floatx4 acc1[4][5][2];
    #pragma unroll
    for (int nc = 0; nc < 4; nc++)
        #pragma unroll
        for (int mi = 0; mi < 5; mi++)
            #pragma unroll
            for (int ni = 0; ni < 2; ni++)
                acc1[nc][mi][ni] = (floatx4){0.f, 0.f, 0.f, 0.f};

    // -------- GEMM1: h(pre-silu) for all 256 hidden cols, K-chunked --------
    for (int k0 = 0; k0 < 256; k0 += 64) {
        __syncthreads();
        #pragma unroll
        for (int i = 0; i < 5; i++) {  // A chunk 160x64
            int idx = i * 256 + t;
            int r = idx >> 3, kc = (idx & 7) * 8;
            *(short8*)&As[r * 72 + kc] =
                *(const short8*)&Abf[(size_t)(e0 + r) * 256 + k0 + kc];
        }
        #pragma unroll
        for (int i = 0; i < 8; i++) {  // B1 chunk 256x64
            int idx = i * 256 + t;
            int r = idx >> 3, kc = (idx & 7) * 8;
            *(short8*)&Bs[r * 72 + kc] =
                *(const short8*)&WT1[(size_t)r * 256 + k0 + kc];
        }
        __syncthreads();
        #pragma unroll
        for (int ks = 0; ks < 2; ks++) {
            int kk = ks * 32 + quad * 8;
            short8 af[5];
            #pragma unroll
            for (int mi = 0; mi < 5; mi++)
                af[mi] = *(const short8*)&As[(wm + mi * 16 + lrow) * 72 + kk];
            #pragma unroll
            for (int nc = 0; nc < 4; nc++) {
                short8 bf0 = *(const short8*)&Bs[(nc * 64 + wn1 + lrow) * 72 + kk];
                short8 bf1 = *(const short8*)&Bs[(nc * 64 + wn1 + 16 + lrow) * 72 + kk];
                #pragma unroll
                for (int mi = 0; mi < 5; mi++) {
                    acc1[nc][mi][0] = __builtin_amdgcn_mfma_f32_16x16x32_bf16(
                        af[mi], bf0, acc1[nc][mi][0], 0, 0, 0);
                    acc1[nc][mi][1] = __builtin_amdgcn_mfma_f32_16x16x32_bf16(
                        af[mi], bf1, acc1[nc][mi][1], 0, 0, 0);
                }
            }
        }
    }

    // -------- GEMM2: m = silu(h) @ W2T, n-chunked over h cols --------
    floatx4 macc[5][4];
    #pragma unroll
    for (int mi = 0; mi < 5; mi++)
        #pragma unroll
        for (int ni = 0; ni < 4; ni++)
            macc[mi][ni] = (floatx4){0.f, 0.f, 0.f, 0.f};

    #pragma unroll
    for (int nc = 0; nc < 4; nc++) {
        __syncthreads();
        #pragma unroll
        for (int mi = 0; mi < 5; mi++) {  // silu -> Hs (aliases As)
            int row = wm + mi * 16 + quad * 4;
            #pragma unroll
            for (int ni = 0; ni < 2; ni++) {
                int col = wn1 + ni * 16 + lrow;
                #pragma unroll
                for (int r = 0; r < 4; r++) {
                    float v = acc1[nc][mi][ni][r];
                    v = v / (1.0f + __expf(-v));
                    Hs[(row + r) * 72 + col] = f2us(v);
                }
            }
        }
        #pragma unroll
        for (int i = 0; i < 4; i++) {  // B2 chunk 128x64
            int idx = i * 256 + t;
            int r = idx >> 3, kc = (idx & 7) * 8;
            *(short8*)&Bs[r * 72 + kc] =
                *(const short8*)&WT2[(size_t)r * 256 + nc * 64 + kc];
        }
        if (nc == 0) {  // stage Y once (region free after GEMM1)
            for (int i = t; i < 160 * 20; i += 256) {
                int e = i / 20, k = i - (i / 20) * 20;
                Ylds[i] = (k < KK) ? Yv[(size_t)(e0 + e) * KK + k] : 0.f;
            }
        }
        __syncthreads();
        #pragma unroll
        for (int ks = 0; ks < 2; ks++) {
            int kk = ks * 32 + quad * 8;
            short8 af[5], bf[4];
            #pragma unroll
            for (int mi = 0; mi < 5; mi++)
                af[mi] = *(const short8*)&Hs[(wm + mi * 16 + lrow) * 72 + kk];
            #pragma unroll
            for (int ni = 0; ni < 4; ni++)
                bf[ni] = *(const short8*)&Bs[(wn2 + ni * 16 + lrow) * 72 + kk];
            #pragma unroll
            for (int mi = 0; mi < 5; mi++)
                #pragma unroll
                for (int ni = 0; ni < 4; ni++)
                    macc[mi][ni] = __builtin_amdgcn_mfma_f32_16x16x32_bf16(
                        af[mi], bf[ni], macc[mi][ni], 0, 0, 0);
        }
    }

    __syncthreads();
    #pragma unroll
    for (int mi = 0; mi < 5; mi++) {  // macc -> Ms bf16 [160][132]
        int row = wm + mi * 16 + quad * 4;
        #pragma unroll
        for (int ni = 0; ni < 4; ni++) {
            int col = wn2 + ni * 16 + lrow;
            #pragma unroll
            for (int r = 0; r < 4; r++)
                Ms[(row + r) * 132 + col] = f2us(macc[mi][ni][r]);
        }
    }
    __syncthreads();

    // -------- aggregation: thread = (node 0..7, col-quad 0..31) --------
    int node = t >> 5;
    int cq = (t & 31) * 4;
    float4 xacc[KK];
    #pragma unroll
    for (int k = 0; k < KK; k++) xacc[k] = make_float4(0.f, 0.f, 0.f, 0.f);

    for (int e = 0; e < NBRS; e++) {
        int eg = node * NBRS + e;
        uint2 mv = *(const uint2*)&Ms[eg * 132 + cq];
        float4 mf;
        mf.x = us2f(mv.x & 0xffffu);
        mf.y = us2f(mv.x >> 16);
        mf.z = us2f(mv.y & 0xffffu);
        mf.w = us2f(mv.y >> 16);
        const float* yp = &Ylds[eg * 20];
        #pragma unroll
        for (int kq = 0; kq < 5; kq++) {
            float4 y = *(const float4*)(yp + kq * 4);
            int k = kq * 4;
            xacc[k + 0].x += y.x * mf.x; xacc[k + 0].y += y.x * mf.y;
            xacc[k + 0].z += y.x * mf.z; xacc[k + 0].w += y.x * mf.w;
            xacc[k + 1].x += y.y * mf.x; xacc[k + 1].y += y.y * mf.y;
            xacc[k + 1].z += y.y * mf.z; xacc[k + 1].w += y.y * mf.w;
            xacc[k + 2].x += y.z * mf.x; xacc[k + 2].y += y.z * mf.y;
            xacc[k + 2].z += y.z * mf.z; xacc[k + 2].w += y.z * mf.w;
            if (kq < 4) {
                xacc[k + 3].x += y.w * mf.x; xacc[k + 3].y += y.w * mf.y;
                xacc[k + 3].z += y.w * mf.z; xacc[k + 3].w += y.w * mf.w;
            }
        }
    }
    const float s = 1.0f / (float)NBRS;
    int ng = blockIdx.x * 8 + node;
    float* xp = x + (size_t)ng * (KK * CC) + cq;
    #pragma unroll
    for (int k = 0; k < KK; k++) {
        float4 old = *(const float4*)(xp + k * CC);
        old.x += xacc[k].x * s; old.y += xacc[k].y * s;
        old.z += xacc[k].z * s; old.w += xacc[k].w * s;
        *(float4*)(xp + k * CC) = old;
    }
}

// ---------------- atom logits ----------------
__global__ void k_logits(const float* __restrict__ x, const float* __restrict__ Wa,
                         const float* __restrict__ ba, float* __restrict__ out) {
    int idx = blockIdx.x * blockDim.x + threadIdx.x;
    if (idx >= NN * MAXZV) return;
    int n = idx / MAXZV, a = idx - n * MAXZV;
    float acc = ba[a];
    const float* hn = x + (size_t)n * (KK * CC);
    for (int c = 0; c < CC; c++) acc += hn[c] * Wa[c * MAXZV + a];
    out[idx] = acc;
}

// ---------------- coord_diff ----------------
__global__ void k_coord(const int* __restrict__ ei, const float* __restrict__ x,
                        const float* __restrict__ wf, const float* __restrict__ dirn,
                        float* __restrict__ out) {
    int n = blockIdx.x;
    int t = threadIdx.x;  // 64
    __shared__ float fs[NBRS];
    __shared__ float wsh[CC];
    wsh[t] = wf[t];
    wsh[t + 64] = wf[t + 64];
    __syncthreads();
    if (t < NBRS) {
        int e = n * NBRS + t;
        int sidx = ei[e];
        const float* xs = x + (size_t)sidx * (KK * CC);
        const float* xd = x + (size_t)n * (KK * CC);
        float acc = 0.0f;
        for (int c = 0; c < CC; c++) acc += (xs[c] - xd[c]) * wsh[c];
        fs[t] = acc;
    }
    __syncthreads();
    if (t < 3) {
        float acc = 0.0f;
        #pragma unroll
        for (int j = 0; j < NBRS; j++) acc += fs[j] * dirn[(size_t)(n * NBRS + j) * 3 + t];
        out[n * 3 + t] = acc;
    }
}

extern "C" void kernel_launch(void* const* d_in, const int* in_sizes, int n_in,
                              void* d_out, int out_size, void* d_ws, size_t ws_size,
                              hipStream_t stream) {
    (void)in_sizes; (void)n_in; (void)out_size; (void)ws_size;
    const float* z       = (const float*)d_in[0];
    const float* frac    = (const float*)d_in[1];
    const int*   atype   = (const int*)d_in[2];
    const float* lengths = (const float*)d_in[4];
    const float* angles  = (const float*)d_in[5];
    const int*   batch   = (const int*)d_in[6];
    const int*   ei      = (const int*)d_in[7];
    const float* emb     = (const float*)d_in[8];
    const float* zproj   = (const float*)d_in[9];
    const float* Wd      = (const float*)d_in[10];
    const float* W1      = (const float*)d_in[11];
    const float* W2      = (const float*)d_in[12];
    const float* Wa      = (const float*)d_in[13];
    const float* ba      = (const float*)d_in[14];
    const float* wf      = (const float*)d_in[15];
    float* out = (float*)d_out;

    float* ws = (float*)d_ws;
    float* pos  = ws; ws += NN * 3 + 4;          // keep 16B alignment
    float* dist = ws; ws += EE;
    float* dirn = ws; ws += EE * 3;
    float* Yv   = ws; ws += (size_t)EE * KK + 4;
    float* Yp   = ws; ws += (size_t)EE * 20;     // CSR-permuted, padded to 20
    float* zc   = ws; ws += N_CRYST * CC;
    float* x    = ws; ws += (size_t)NN * KK * CC;
    int* rowptr = (int*)ws;                       // 64*33
    int* origid = rowptr + 64 * 33 + 3;           // EE (16B align kept)
    ushort_t* Abf  = (ushort_t*)(origid + EE);    // [E][256]: 0-127 s, 128-255 rbf
    ushort_t* WT1  = Abf + (size_t)EE * 256;      // [8][256][256]
    ushort_t* WT2  = WT1 + (size_t)NLAYERS * 256 * 256;  // [8][128][256]

    k_pos<<<NN / 256, 256, 0, stream>>>(frac, lengths, angles, batch, pos);
    k_edge<<<EE / 256, 256, 0, stream>>>(ei, pos, dist, dirn, Yv);
    k_csr<<<N_CRYST, 64, 0, stream>>>(ei, Yv, rowptr, origid, Yp);
    k_rbfA<<<(EE * NBASIS) / 256, 256, 0, stream>>>(dist, Abf);
    k_wt<<<(NLAYERS * (HIDDIM * 256 + CC * HIDDIM)) / 256, 256, 0, stream>>>(W1, Wd, W2, WT1, WT2);
    k_zc<<<(N_CRYST * CC) / 256, 256, 0, stream>>>(z, zproj, zc);
    k_xinit<<<(NN * KK * CC) / 256, 256, 0, stream>>>(atype, batch, emb, zc, x);

    for (int l = 0; l < NLAYERS; l++) {
        k_s2<<<512, 256, 0, stream>>>(rowptr, origid, Yp, x, Abf);
        k_fused<<<256, 256, 0, stream>>>(Abf,
                                         WT1 + (size_t)l * 256 * 256,
                                         WT2 + (size_t)l * CC * HIDDIM,
                                         Yv, x);
    }

    k_coord<<<NN, 64, 0, stream>>>(ei, x, wf, dirn, out);
    k_logits<<<(NN * MAXZV) / 256, 256, 0, stream>>>(x, Wa, ba, out + NN * 3);
}